// Round 12
// baseline (920.764 us; speedup 1.0000x reference)
//
#include <hip/hip_runtime.h>
#include <math.h>

#define C 128
#define K 16

typedef unsigned short ushort_t;
typedef unsigned int u32;
typedef float f32x4 __attribute__((ext_vector_type(4)));
typedef _Float16 f16x8 __attribute__((ext_vector_type(8)));

union U8h { _Float16 h[8]; uint4 u; };

__device__ __forceinline__ float f16tof(ushort_t b) {
    _Float16 h = __builtin_bit_cast(_Float16, b); return (float)h;
}
__device__ __forceinline__ ushort_t ftof16(float f) {
    _Float16 h = (_Float16)f; return __builtin_bit_cast(ushort_t, h);
}
__device__ __forceinline__ f32x4 mfma16(f16x8 a, f16x8 b, f32x4 c) {
    return __builtin_amdgcn_mfma_f32_16x16x32_f16(a, b, c, 0, 0, 0);
}

// ---------------------------------------------------------------------------
// Prep: transpose+convert 4 weight matrices fp32 -> fp16, WT[n][e] layout.
// ---------------------------------------------------------------------------
__global__ __launch_bounds__(128) void k_prep(
    const float* __restrict__ s0, const float* __restrict__ s1,
    const float* __restrict__ s2, const float* __restrict__ s3,
    ushort_t* __restrict__ d0, ushort_t* __restrict__ d1,
    ushort_t* __restrict__ d2, ushort_t* __restrict__ d3)
{
    const int m = blockIdx.x >> 7, n = blockIdx.x & 127, e = threadIdx.x;
    const float* s = (m==0) ? s0 : (m==1) ? s1 : (m==2) ? s2 : s3;
    ushort_t*   d = (m==0) ? d0 : (m==1) ? d1 : (m==2) ? d2 : d3;
    d[n*C + e] = ftof16(s[e*C + n]);
}

// ---------------------------------------------------------------------------
// Kernel 1: h = x@W_top + b; phi/psi/alpha = h@W_* + b   via f16 MFMA.
// ---------------------------------------------------------------------------
__global__ __launch_bounds__(512) void k_qkv2(
    const float* __restrict__ x,
    const ushort_t* __restrict__ WTt, const float* __restrict__ bt,
    const ushort_t* __restrict__ WTp, const float* __restrict__ bp,
    const ushort_t* __restrict__ WTs, const float* __restrict__ bs,
    const ushort_t* __restrict__ WTa, const float* __restrict__ ba,
    ushort_t* __restrict__ phiB, ushort_t* __restrict__ psiB,
    ushort_t* __restrict__ alfB)
{
    __shared__ ushort_t sX[64*C];
    __shared__ ushort_t sH[64*C];
    const int tid = threadIdx.x, lane = tid & 63, wv = tid >> 6;
    const int ncol = (wv<<4) + (lane&15), arow = lane&15;
    const int kgrp = lane>>4, krow0 = kgrp<<3;
    const int r0 = blockIdx.x * 64;

    {
        const int rX = tid>>3, cX = (tid&7)<<4;
        const float* xp = &x[(size_t)(r0+rX)*C + cX];
        #pragma unroll
        for (int hf = 0; hf < 2; ++hf) {
            const float4 a  = *(const float4*)&xp[hf*8 + 0];
            const float4 b2 = *(const float4*)&xp[hf*8 + 4];
            U8h v;
            v.h[0]=(_Float16)a.x;  v.h[1]=(_Float16)a.y;
            v.h[2]=(_Float16)a.z;  v.h[3]=(_Float16)a.w;
            v.h[4]=(_Float16)b2.x; v.h[5]=(_Float16)b2.y;
            v.h[6]=(_Float16)b2.z; v.h[7]=(_Float16)b2.w;
            const int col = cX + hf*8;
            *(uint4*)&sX[(rX<<7) + (col ^ ((rX&7)<<3))] = v.u;
        }
    }
    __syncthreads();

    {
        f16x8 bf[4]; f32x4 hacc[4];
        #pragma unroll
        for (int kk = 0; kk < 4; ++kk)
            bf[kk] = *(const f16x8*)&WTt[(size_t)ncol*C + (kk<<5) + krow0];
        #pragma unroll
        for (int m = 0; m < 4; ++m) hacc[m] = (f32x4){0.f,0.f,0.f,0.f};
        __builtin_amdgcn_s_setprio(1);
        #pragma unroll
        for (int m = 0; m < 4; ++m)
            #pragma unroll
            for (int kk = 0; kk < 4; ++kk) {
                const int row = (m<<4) + arow;
                const f16x8 af = *(const f16x8*)&sX[(row<<7) + (((kk<<5)+krow0) ^ ((arow&7)<<3))];
                hacc[m] = mfma16(af, bf[kk], hacc[m]);
            }
        __builtin_amdgcn_s_setprio(0);
        const float btc = bt[ncol];
        #pragma unroll
        for (int m = 0; m < 4; ++m)
            #pragma unroll
            for (int r = 0; r < 4; ++r) {
                const int row = (m<<4) + (kgrp<<2) + r;
                sH[(row<<7) + (ncol ^ ((row&7)<<3))] = ftof16(hacc[m][r] + btc);
            }
    }
    __syncthreads();

#define OGEMM(WT_, b_, o_)                                                    \
    {                                                                         \
        f16x8 wf[4]; f32x4 oacc[4];                                           \
        _Pragma("unroll")                                                     \
        for (int kk = 0; kk < 4; ++kk)                                        \
            wf[kk] = *(const f16x8*)&WT_[(size_t)ncol*C + (kk<<5) + krow0];   \
        _Pragma("unroll")                                                     \
        for (int m = 0; m < 4; ++m) oacc[m] = (f32x4){0.f,0.f,0.f,0.f};      \
        __builtin_amdgcn_s_setprio(1);                                        \
        _Pragma("unroll")                                                     \
        for (int m = 0; m < 4; ++m)                                           \
            _Pragma("unroll")                                                 \
            for (int kk = 0; kk < 4; ++kk) {                                  \
                const int row = (m<<4) + arow;                                \
                const f16x8 af = *(const f16x8*)&sH[(row<<7) + (((kk<<5)+krow0) ^ ((arow&7)<<3))]; \
                oacc[m] = mfma16(af, wf[kk], oacc[m]);                        \
            }                                                                 \
        __builtin_amdgcn_s_setprio(0);                                        \
        const float bc = b_[ncol];                                            \
        _Pragma("unroll")                                                     \
        for (int m = 0; m < 4; ++m)                                           \
            _Pragma("unroll")                                                 \
            for (int r = 0; r < 4; ++r) {                                     \
                const int row = (m<<4) + (kgrp<<2) + r;                       \
                o_[(size_t)(r0+row)*C + ncol] = ftof16(oacc[m][r] + bc);      \
            }                                                                 \
    }
    OGEMM(WTp, bp, phiB)
    OGEMM(WTs, bs, psiB)
    OGEMM(WTa, ba, alfB)
#undef OGEMM
}

// ---------------------------------------------------------------------------
// Kernel 2: WAVE-AUTONOMOUS fused vector attention -> yB (f16).
// 256 thr / 4 waves; each wave processes ONE POINT per iteration with
// PRIVATE LDS slices (sT/sA/sP, 12KB/wave). ZERO __syncthreads in the loop:
// same-wave LDS write->read is ordered by the in-order LDS pipe (lgkmcnt).
// A-frags read once per GEMM (4 ds_read_b128), reused for all 8 col-tiles;
// weights streamed per col-tile (runtime loop, unroll 2 -> low reg pressure).
// ---------------------------------------------------------------------------
__global__ __launch_bounds__(256, 2) void k_attn_w(
    const ushort_t* __restrict__ phiB, const ushort_t* __restrict__ psiB,
    const ushort_t* __restrict__ alfB,
    const float* __restrict__ coords, const int* __restrict__ nidx,
    const float* __restrict__ Wd1, const float* __restrict__ bd1,
    const ushort_t* __restrict__ WTd2, const float* __restrict__ bd2,
    const ushort_t* __restrict__ WTg1, const float* __restrict__ bg1,
    const ushort_t* __restrict__ WTg2,
    ushort_t* __restrict__ yB, int npts)
{
    __shared__ ushort_t sT[4][16*C];   // t1, then u     (per-wave slice)
    __shared__ ushort_t sA[4][16*C];   // attn
    __shared__ ushort_t sP[4][16*C];   // pos (f16)
    __shared__ float    sW1b[512];     // Wd1 (384) + bd1 (128), shared RO

    const int tid  = threadIdx.x, lane = tid & 63, wid = tid >> 6;
    ushort_t* T = sT[wid];
    ushort_t* A = sA[wid];
    ushort_t* P = sP[wid];

    for (int i = tid; i < 512; i += 256)
        sW1b[i] = (i < 384) ? Wd1[i] : bd1[i - 384];
    __syncthreads();                       // the ONLY barrier

    const int arow  = lane & 15;           // A-frag row / C-frag col
    const int kgrp  = lane >> 4;           // 0..3
    const int krow0 = kgrp << 3;
    const int rb    = kgrp << 2;           // C-frag row base
    const int trow  = lane >> 2;           // t1 row 0..15
    const int tcol  = (lane & 3) << 5;     // t1 col base 0/32/64/96

    const int gw     = blockIdx.x * 4 + wid;
    const int stride = gridDim.x * 4;

    for (int p = gw; p < npts; p += stride) {
        // ---- phase 1: t1 = relu(rel @ Wd1 + bd1) -> T (16x128 f16) ----
        {
            const int jt = nidx[(size_t)p*K + trow];
            const float rx = coords[(size_t)p*3+0] - coords[(size_t)jt*3+0];
            const float ry = coords[(size_t)p*3+1] - coords[(size_t)jt*3+1];
            const float rz = coords[(size_t)p*3+2] - coords[(size_t)jt*3+2];
            #pragma unroll
            for (int s = 0; s < 4; ++s) {
                U8h h;
                #pragma unroll
                for (int z = 0; z < 8; ++z) {
                    const int c = tcol + (s<<3) + z;
                    float t = fmaf(rx, sW1b[c],
                              fmaf(ry, sW1b[128+c],
                              fmaf(rz, sW1b[256+c], sW1b[384+c])));
                    h.h[z] = (_Float16)fmaxf(t, 0.f);
                }
                *(uint4*)&T[(trow<<7) + ((tcol + (s<<3)) ^ ((trow&7)<<3))] = h.u;
            }
        }

        const int4 j4 = *(const int4*)&nidx[(size_t)p*K + rb];

        // ---- phase 2: pos = t1@Wd2+bd2 ; attn = phi - psi + pos ----
        {
            f16x8 af0 = *(const f16x8*)&T[(arow<<7) + (( 0 + krow0) ^ ((arow&7)<<3))];
            f16x8 af1 = *(const f16x8*)&T[(arow<<7) + ((32 + krow0) ^ ((arow&7)<<3))];
            f16x8 af2 = *(const f16x8*)&T[(arow<<7) + ((64 + krow0) ^ ((arow&7)<<3))];
            f16x8 af3 = *(const f16x8*)&T[(arow<<7) + ((96 + krow0) ^ ((arow&7)<<3))];
            #pragma unroll 2
            for (int ct = 0; ct < 8; ++ct) {
                const int col = (ct<<4) + arow;
                const ushort_t* wp = &WTd2[(size_t)col*C + krow0];
                const f16x8 w0 = *(const f16x8*)&wp[0];
                const f16x8 w1 = *(const f16x8*)&wp[32];
                const f16x8 w2 = *(const f16x8*)&wp[64];
                const f16x8 w3 = *(const f16x8*)&wp[96];
                const float bd2c = bd2[col];
                const ushort_t phv = phiB[(size_t)p*C + col];
                const ushort_t ps0 = psiB[(size_t)j4.x*C + col];
                const ushort_t ps1 = psiB[(size_t)j4.y*C + col];
                const ushort_t ps2 = psiB[(size_t)j4.z*C + col];
                const ushort_t ps3 = psiB[(size_t)j4.w*C + col];
                f32x4 acc = (f32x4){0.f,0.f,0.f,0.f};
                acc = mfma16(af0, w0, acc);
                acc = mfma16(af1, w1, acc);
                acc = mfma16(af2, w2, acc);
                acc = mfma16(af3, w3, acc);
                const float ph = f16tof(phv);
                #pragma unroll
                for (int r = 0; r < 4; ++r) {
                    const int row = rb + r;
                    const int si  = (row<<7) + (col ^ ((row&7)<<3));
                    const float pv = acc[r] + bd2c;
                    P[si] = ftof16(pv);
                    const float psr = (r==0) ? f16tof(ps0) : (r==1) ? f16tof(ps1)
                                    : (r==2) ? f16tof(ps2) : f16tof(ps3);
                    A[si] = ftof16(ph - psr + pv);
                }
            }
        }

        // ---- phase 3: u = relu(attn@Wg1+bg1) -> T (overwrite) ----
        {
            f16x8 ag0 = *(const f16x8*)&A[(arow<<7) + (( 0 + krow0) ^ ((arow&7)<<3))];
            f16x8 ag1 = *(const f16x8*)&A[(arow<<7) + ((32 + krow0) ^ ((arow&7)<<3))];
            f16x8 ag2 = *(const f16x8*)&A[(arow<<7) + ((64 + krow0) ^ ((arow&7)<<3))];
            f16x8 ag3 = *(const f16x8*)&A[(arow<<7) + ((96 + krow0) ^ ((arow&7)<<3))];
            #pragma unroll 2
            for (int ct = 0; ct < 8; ++ct) {
                const int col = (ct<<4) + arow;
                const ushort_t* wp = &WTg1[(size_t)col*C + krow0];
                const f16x8 w0 = *(const f16x8*)&wp[0];
                const f16x8 w1 = *(const f16x8*)&wp[32];
                const f16x8 w2 = *(const f16x8*)&wp[64];
                const f16x8 w3 = *(const f16x8*)&wp[96];
                const float bg1c = bg1[col];
                f32x4 acc = (f32x4){0.f,0.f,0.f,0.f};
                acc = mfma16(ag0, w0, acc);
                acc = mfma16(ag1, w1, acc);
                acc = mfma16(ag2, w2, acc);
                acc = mfma16(ag3, w3, acc);
                #pragma unroll
                for (int r = 0; r < 4; ++r) {
                    const int row = rb + r;
                    T[(row<<7) + (col ^ ((row&7)<<3))] =
                        ftof16(fmaxf(acc[r] + bg1c, 0.f));
                }
            }
        }

        // ---- phase 4: logits = u@Wg2 ; softmax over K ; y -> yB ----
        {
            f16x8 au0 = *(const f16x8*)&T[(arow<<7) + (( 0 + krow0) ^ ((arow&7)<<3))];
            f16x8 au1 = *(const f16x8*)&T[(arow<<7) + ((32 + krow0) ^ ((arow&7)<<3))];
            f16x8 au2 = *(const f16x8*)&T[(arow<<7) + ((64 + krow0) ^ ((arow&7)<<3))];
            f16x8 au3 = *(const f16x8*)&T[(arow<<7) + ((96 + krow0) ^ ((arow&7)<<3))];
            #pragma unroll 2
            for (int ct = 0; ct < 8; ++ct) {
                const int col = (ct<<4) + arow;
                const ushort_t* wp = &WTg2[(size_t)col*C + krow0];
                const f16x8 w0 = *(const f16x8*)&wp[0];
                const f16x8 w1 = *(const f16x8*)&wp[32];
                const f16x8 w2 = *(const f16x8*)&wp[64];
                const f16x8 w3 = *(const f16x8*)&wp[96];
                const ushort_t a0 = alfB[(size_t)j4.x*C + col];
                const ushort_t a1 = alfB[(size_t)j4.y*C + col];
                const ushort_t a2 = alfB[(size_t)j4.z*C + col];
                const ushort_t a3 = alfB[(size_t)j4.w*C + col];
                f32x4 lg = (f32x4){0.f,0.f,0.f,0.f};
                lg = mfma16(au0, w0, lg);
                lg = mfma16(au1, w1, lg);
                lg = mfma16(au2, w2, lg);
                lg = mfma16(au3, w3, lg);
                float mx = fmaxf(fmaxf(lg[0], lg[1]), fmaxf(lg[2], lg[3]));
                mx = fmaxf(mx, __shfl_xor(mx, 16));
                mx = fmaxf(mx, __shfl_xor(mx, 32));
                const float e0 = __expf(lg[0]-mx), e1 = __expf(lg[1]-mx);
                const float e2 = __expf(lg[2]-mx), e3 = __expf(lg[3]-mx);
                float den = e0 + e1 + e2 + e3;
                den += __shfl_xor(den, 16);
                den += __shfl_xor(den, 32);
                const float inv = 1.0f / den;
                float yp = 0.f;
                #pragma unroll
                for (int r = 0; r < 4; ++r) {
                    const int row = rb + r;
                    const float pr = f16tof(P[(row<<7) + (col ^ ((row&7)<<3))]);
                    const float av = (r==0) ? f16tof(a0) : (r==1) ? f16tof(a1)
                                   : (r==2) ? f16tof(a2) : f16tof(a3);
                    const float ee = (r==0) ? e0 : (r==1) ? e1 : (r==2) ? e2 : e3;
                    yp = fmaf(ee, av + pr, yp);
                }
                yp *= inv;
                yp += __shfl_xor(yp, 16);
                yp += __shfl_xor(yp, 32);
                if (lane < 16)
                    yB[(size_t)p*C + col] = ftof16(yp);
            }
        }
    }
}

// ---------------------------------------------------------------------------
// Kernel 3: out = y @ W_down + b_down + x   (f16 MFMA GEMM, 64 rows/block)
// ---------------------------------------------------------------------------
__global__ __launch_bounds__(512) void k_down(
    const ushort_t* __restrict__ yB,
    const ushort_t* __restrict__ WTdn, const float* __restrict__ bdn,
    const float* __restrict__ x, float* __restrict__ out)
{
    __shared__ ushort_t sY[64*C];
    const int tid = threadIdx.x, lane = tid & 63, wv = tid >> 6;
    const int ncol = (wv<<4) + (lane&15), arow = lane&15;
    const int kgrp = lane>>4, krow0 = kgrp<<3;
    const int r0 = blockIdx.x * 64;

    {
        const int rY = tid>>3, cY = (tid&7)<<4;
        #pragma unroll
        for (int hf = 0; hf < 2; ++hf) {
            const uint4 v = *(const uint4*)&yB[(size_t)(r0+rY)*C + cY + hf*8];
            *(uint4*)&sY[(rY<<7) + ((cY + hf*8) ^ ((rY&7)<<3))] = v;
        }
    }
    __syncthreads();

    f16x8 wf[4]; f32x4 oacc[4];
    #pragma unroll
    for (int kk = 0; kk < 4; ++kk)
        wf[kk] = *(const f16x8*)&WTdn[(size_t)ncol*C + (kk<<5) + krow0];
    #pragma unroll
    for (int m = 0; m < 4; ++m) oacc[m] = (f32x4){0.f,0.f,0.f,0.f};
    __builtin_amdgcn_s_setprio(1);
    #pragma unroll
    for (int m = 0; m < 4; ++m)
        #pragma unroll
        for (int kk = 0; kk < 4; ++kk) {
            const int row = (m<<4) + arow;
            const f16x8 af = *(const f16x8*)&sY[(row<<7) + (((kk<<5)+krow0) ^ ((arow&7)<<3))];
            oacc[m] = mfma16(af, wf[kk], oacc[m]);
        }
    __builtin_amdgcn_s_setprio(0);
    const float bc = bdn[ncol];
    #pragma unroll
    for (int m = 0; m < 4; ++m)
        #pragma unroll
        for (int r = 0; r < 4; ++r) {
            const int row = (m<<4) + (kgrp<<2) + r;
            const size_t idx = (size_t)(r0+row)*C + ncol;
            out[idx] = oacc[m][r] + bc + x[idx];
        }
}

// ---------------------------------------------------------------------------
extern "C" void kernel_launch(void* const* d_in, const int* in_sizes, int n_in,
                              void* d_out, int out_size, void* d_ws, size_t ws_size,
                              hipStream_t stream)
{
    const float* x      = (const float*)d_in[0];
    const float* coords = (const float*)d_in[1];
    const int*   nidx   = (const int*)d_in[2];
    const float* W_top  = (const float*)d_in[3];
    const float* b_top  = (const float*)d_in[4];
    const float* W_down = (const float*)d_in[5];
    const float* b_down = (const float*)d_in[6];
    const float* W_phi  = (const float*)d_in[7];
    const float* b_phi  = (const float*)d_in[8];
    const float* W_psi  = (const float*)d_in[9];
    const float* b_psi  = (const float*)d_in[10];
    const float* W_alpha= (const float*)d_in[11];
    const float* b_alpha= (const float*)d_in[12];
    const float* W_d1   = (const float*)d_in[13];
    const float* b_d1   = (const float*)d_in[14];
    const float* W_d2   = (const float*)d_in[15];
    const float* b_d2   = (const float*)d_in[16];
    const float* W_g1   = (const float*)d_in[17];
    const float* b_g1   = (const float*)d_in[18];
    const float* W_g2   = (const float*)d_in[19];
    const float* b_g2   = (const float*)d_in[20];
    (void)b_g2; // softmax shift-invariant

    const int N = in_sizes[0] / C;

    ushort_t* WTt  = (ushort_t*)d_ws;
    ushort_t* WTp  = WTt  + C*C;
    ushort_t* WTs  = WTp  + C*C;
    ushort_t* WTa  = WTs  + C*C;
    ushort_t* WTd2 = WTa  + C*C;
    ushort_t* WTg1 = WTd2 + C*C;
    ushort_t* WTg2 = WTg1 + C*C;
    ushort_t* WTdn = WTg2 + C*C;
    ushort_t* phiB = WTdn + C*C;
    ushort_t* psiB = phiB + (size_t)N*C;
    ushort_t* alfB = psiB + (size_t)N*C;
    ushort_t* yB   = alfB + (size_t)N*C;
    float* out = (float*)d_out;

    hipLaunchKernelGGL(k_prep, dim3(4*C), dim3(C), 0, stream,
        W_top, W_phi, W_psi, W_alpha, WTt, WTp, WTs, WTa);
    hipLaunchKernelGGL(k_prep, dim3(4*C), dim3(C), 0, stream,
        W_d2, W_g1, W_g2, W_down, WTd2, WTg1, WTg2, WTdn);

    hipLaunchKernelGGL(k_qkv2, dim3(N / 64), dim3(512), 0, stream,
        x, WTt, b_top, WTp, b_phi, WTs, b_psi, WTa, b_alpha,
        phiB, psiB, alfB);

    hipLaunchKernelGGL(k_attn_w, dim3(768), dim3(256), 0, stream,
        phiB, psiB, alfB, coords, nidx,
        W_d1, b_d1, WTd2, b_d2, WTg1, b_g1, WTg2,
        yB, N);

    hipLaunchKernelGGL(k_down, dim3(N / 64), dim3(512), 0, stream,
        yB, WTdn, b_down, x, out);
}

// Round 13
// 578.816 us; speedup vs baseline: 1.5908x; 1.5908x over previous
//
#include <hip/hip_runtime.h>
#include <math.h>

#define C 128
#define K 16
#define M 4              // points per group
#define ROWS 64          // M*K rows per tile

typedef unsigned short ushort_t;
typedef unsigned int u32;
typedef float f32x4 __attribute__((ext_vector_type(4)));
typedef _Float16 f16x8 __attribute__((ext_vector_type(8)));

union U8h { _Float16 h[8]; uint4 u; };

__device__ __forceinline__ float f16tof(ushort_t b) {
    _Float16 h = __builtin_bit_cast(_Float16, b); return (float)h;
}
__device__ __forceinline__ ushort_t ftof16(float f) {
    _Float16 h = (_Float16)f; return __builtin_bit_cast(ushort_t, h);
}
__device__ __forceinline__ f32x4 mfma16(f16x8 a, f16x8 b, f32x4 c) {
    return __builtin_amdgcn_mfma_f32_16x16x32_f16(a, b, c, 0, 0, 0);
}

// ---------------------------------------------------------------------------
// Prep: transpose+convert 4 weight matrices fp32 -> fp16, WT[n][e] layout.
// ---------------------------------------------------------------------------
__global__ __launch_bounds__(128) void k_prep(
    const float* __restrict__ s0, const float* __restrict__ s1,
    const float* __restrict__ s2, const float* __restrict__ s3,
    ushort_t* __restrict__ d0, ushort_t* __restrict__ d1,
    ushort_t* __restrict__ d2, ushort_t* __restrict__ d3)
{
    const int m = blockIdx.x >> 7, n = blockIdx.x & 127, e = threadIdx.x;
    const float* s = (m==0) ? s0 : (m==1) ? s1 : (m==2) ? s2 : s3;
    ushort_t*   d = (m==0) ? d0 : (m==1) ? d1 : (m==2) ? d2 : d3;
    d[n*C + e] = ftof16(s[e*C + n]);
}

// ---------------------------------------------------------------------------
// Kernel 1: h = x@W_top + b; phi/psi/alpha = h@W_* + b   via f16 MFMA.
// ---------------------------------------------------------------------------
__global__ __launch_bounds__(512) void k_qkv2(
    const float* __restrict__ x,
    const ushort_t* __restrict__ WTt, const float* __restrict__ bt,
    const ushort_t* __restrict__ WTp, const float* __restrict__ bp,
    const ushort_t* __restrict__ WTs, const float* __restrict__ bs,
    const ushort_t* __restrict__ WTa, const float* __restrict__ ba,
    ushort_t* __restrict__ phiB, ushort_t* __restrict__ psiB,
    ushort_t* __restrict__ alfB)
{
    __shared__ ushort_t sX[64*C];
    __shared__ ushort_t sH[64*C];
    const int tid = threadIdx.x, lane = tid & 63, wv = tid >> 6;
    const int ncol = (wv<<4) + (lane&15), arow = lane&15;
    const int kgrp = lane>>4, krow0 = kgrp<<3;
    const int r0 = blockIdx.x * 64;

    {
        const int rX = tid>>3, cX = (tid&7)<<4;
        const float* xp = &x[(size_t)(r0+rX)*C + cX];
        #pragma unroll
        for (int hf = 0; hf < 2; ++hf) {
            const float4 a  = *(const float4*)&xp[hf*8 + 0];
            const float4 b2 = *(const float4*)&xp[hf*8 + 4];
            U8h v;
            v.h[0]=(_Float16)a.x;  v.h[1]=(_Float16)a.y;
            v.h[2]=(_Float16)a.z;  v.h[3]=(_Float16)a.w;
            v.h[4]=(_Float16)b2.x; v.h[5]=(_Float16)b2.y;
            v.h[6]=(_Float16)b2.z; v.h[7]=(_Float16)b2.w;
            const int col = cX + hf*8;
            *(uint4*)&sX[(rX<<7) + (col ^ ((rX&7)<<3))] = v.u;
        }
    }
    __syncthreads();

    {
        f16x8 bf[4]; f32x4 hacc[4];
        #pragma unroll
        for (int kk = 0; kk < 4; ++kk)
            bf[kk] = *(const f16x8*)&WTt[(size_t)ncol*C + (kk<<5) + krow0];
        #pragma unroll
        for (int m = 0; m < 4; ++m) hacc[m] = (f32x4){0.f,0.f,0.f,0.f};
        __builtin_amdgcn_s_setprio(1);
        #pragma unroll
        for (int m = 0; m < 4; ++m)
            #pragma unroll
            for (int kk = 0; kk < 4; ++kk) {
                const int row = (m<<4) + arow;
                const f16x8 af = *(const f16x8*)&sX[(row<<7) + (((kk<<5)+krow0) ^ ((arow&7)<<3))];
                hacc[m] = mfma16(af, bf[kk], hacc[m]);
            }
        __builtin_amdgcn_s_setprio(0);
        const float btc = bt[ncol];
        #pragma unroll
        for (int m = 0; m < 4; ++m)
            #pragma unroll
            for (int r = 0; r < 4; ++r) {
                const int row = (m<<4) + (kgrp<<2) + r;
                sH[(row<<7) + (ncol ^ ((row&7)<<3))] = ftof16(hacc[m][r] + btc);
            }
    }
    __syncthreads();

#define OGEMM(WT_, b_, o_)                                                    \
    {                                                                         \
        f16x8 wf[4]; f32x4 oacc[4];                                           \
        _Pragma("unroll")                                                     \
        for (int kk = 0; kk < 4; ++kk)                                        \
            wf[kk] = *(const f16x8*)&WT_[(size_t)ncol*C + (kk<<5) + krow0];   \
        _Pragma("unroll")                                                     \
        for (int m = 0; m < 4; ++m) oacc[m] = (f32x4){0.f,0.f,0.f,0.f};      \
        __builtin_amdgcn_s_setprio(1);                                        \
        _Pragma("unroll")                                                     \
        for (int m = 0; m < 4; ++m)                                           \
            _Pragma("unroll")                                                 \
            for (int kk = 0; kk < 4; ++kk) {                                  \
                const int row = (m<<4) + arow;                                \
                const f16x8 af = *(const f16x8*)&sH[(row<<7) + (((kk<<5)+krow0) ^ ((arow&7)<<3))]; \
                oacc[m] = mfma16(af, wf[kk], oacc[m]);                        \
            }                                                                 \
        __builtin_amdgcn_s_setprio(0);                                        \
        const float bc = b_[ncol];                                            \
        _Pragma("unroll")                                                     \
        for (int m = 0; m < 4; ++m)                                           \
            _Pragma("unroll")                                                 \
            for (int r = 0; r < 4; ++r) {                                     \
                const int row = (m<<4) + (kgrp<<2) + r;                       \
                o_[(size_t)(r0+row)*C + ncol] = ftof16(oacc[m][r] + bc);      \
            }                                                                 \
    }
    OGEMM(WTp, bp, phiB)
    OGEMM(WTs, bs, psiB)
    OGEMM(WTa, ba, alfB)
#undef OGEMM
}

// ---------------------------------------------------------------------------
// Kernel 2: fused vector attention -> yB (f16). MINIMAL cross-phase state:
//  - no persistent weight fragments (streamed per kk inside each MFMA loop)
//  - pos parked in LDS (f16), not registers
//  - psi/phi/alpha loaded AT USE in pointwise code (short live ranges)
//  - t1 single f16
// Peak demand ~75 regs -> genuinely fits the (512,4) 128-reg wave budget:
// 16 waves/CU (2 x 8-wave blocks) with NO spill.
// ---------------------------------------------------------------------------
__global__ __launch_bounds__(512, 4) void k_attn11(
    const ushort_t* __restrict__ phiB, const ushort_t* __restrict__ psiB,
    const ushort_t* __restrict__ alfB,
    const float* __restrict__ coords, const int* __restrict__ nidx,
    const float* __restrict__ Wd1, const float* __restrict__ bd1,
    const ushort_t* __restrict__ WTd2, const float* __restrict__ bd2,
    const ushort_t* __restrict__ WTg1, const float* __restrict__ bg1,
    const ushort_t* __restrict__ WTg2,
    ushort_t* __restrict__ yB,
    int ngroups, int gpb)
{
    __shared__ ushort_t sT[ROWS*C];   // t1, then u
    __shared__ ushort_t sA[ROWS*C];   // attn
    __shared__ ushort_t sP[ROWS*C];   // pos (f16)
    __shared__ float    sW1b[512];    // Wd1 (384) + bd1 (128)

    const int tid  = threadIdx.x, lane = tid & 63, wv = tid >> 6;
    const int ncol = (wv<<4) + (lane&15);
    const int arow = lane & 15;
    const int kgrp = lane >> 4, krow0 = kgrp << 3;
    const int rb   = kgrp << 2;           // C-frag row base within m-tile
    const int grow = tid >> 3;            // t1 row 0..63
    const int gpt  = grow >> 4;           // point-in-group 0..3
    const int gk   = grow & 15;           // neighbor 0..15
    const int gc   = (tid & 7) << 4;      // 16-ch slice base

    const int g0 = blockIdx.x * gpb;
    if (g0 >= ngroups) return;
    const int gend = (g0 + gpb < ngroups) ? (g0 + gpb) : ngroups;

    for (int i = tid; i < 512; i += 256)
        if (i < 512) sW1b[i] = (i < 384) ? Wd1[i] : bd1[i - 384];

    const float bd2c = bd2[ncol];
    const float bg1c = bg1[ncol];

    __syncthreads();   // sW1b staged

    for (int g = g0; g < gend; ++g) {
        const int p0 = g * M;

        // ======== phase 1: t1 = relu(rel@Wd1+bd1) -> sT (single f16) =====
        {
            const int pt = p0 + gpt;
            const int jt = nidx[(size_t)pt*K + gk];
            const float rx = coords[(size_t)pt*3+0] - coords[(size_t)jt*3+0];
            const float ry = coords[(size_t)pt*3+1] - coords[(size_t)jt*3+1];
            const float rz = coords[(size_t)pt*3+2] - coords[(size_t)jt*3+2];
            #pragma unroll
            for (int s = 0; s < 2; ++s) {
                U8h h;
                #pragma unroll
                for (int z = 0; z < 8; ++z) {
                    const int c = gc + (s<<3) + z;
                    float t = fmaf(rx, sW1b[c],
                              fmaf(ry, sW1b[128+c],
                              fmaf(rz, sW1b[256+c], sW1b[384+c])));
                    h.h[z] = (_Float16)fmaxf(t, 0.f);
                }
                *(uint4*)&sT[(grow<<7) + ((gc + (s<<3)) ^ ((grow&7)<<3))] = h.u;
            }
        }
        __syncthreads();                                        // S1

        // ======== phase 2: pos = t1@Wd2+b ; attn = phi-psi+pos ========
        {
            f32x4 acc[M];
            #pragma unroll
            for (int m = 0; m < M; ++m) acc[m] = (f32x4){0.f,0.f,0.f,0.f};
            __builtin_amdgcn_s_setprio(1);
            #pragma unroll
            for (int kk = 0; kk < 4; ++kk) {
                const f16x8 w = *(const f16x8*)&WTd2[(size_t)ncol*C + (kk<<5) + krow0];
                #pragma unroll
                for (int m = 0; m < M; ++m) {
                    const f16x8 af = *(const f16x8*)&sT[(((m<<4)+arow)<<7) + (((kk<<5)+krow0) ^ ((arow&7)<<3))];
                    acc[m] = mfma16(af, w, acc[m]);
                }
            }
            __builtin_amdgcn_s_setprio(0);

            #pragma unroll
            for (int m = 0; m < M; ++m) {
                const float ph = f16tof(phiB[(size_t)(p0+m)*C + ncol]);
                const int4 j4 = *(const int4*)&nidx[(size_t)(p0+m)*K + rb];
                #pragma unroll
                for (int r = 0; r < 4; ++r) {
                    const int j = (r==0) ? j4.x : (r==1) ? j4.y : (r==2) ? j4.z : j4.w;
                    const float ps = f16tof(psiB[(size_t)j*C + ncol]);
                    const int row = (m<<4) + rb + r;
                    const int si  = (row<<7) + (ncol ^ ((row&7)<<3));
                    const float pv = acc[m][r] + bd2c;
                    sP[si] = ftof16(pv);
                    sA[si] = ftof16(ph - ps + pv);
                }
            }
        }
        __syncthreads();                                        // S2

        // ======== phase 3: u = relu(attn@Wg1+b) -> sT (overwrite) ========
        {
            f32x4 acc[M];
            #pragma unroll
            for (int m = 0; m < M; ++m) acc[m] = (f32x4){0.f,0.f,0.f,0.f};
            __builtin_amdgcn_s_setprio(1);
            #pragma unroll
            for (int kk = 0; kk < 4; ++kk) {
                const f16x8 w = *(const f16x8*)&WTg1[(size_t)ncol*C + (kk<<5) + krow0];
                #pragma unroll
                for (int m = 0; m < M; ++m) {
                    const f16x8 af = *(const f16x8*)&sA[(((m<<4)+arow)<<7) + (((kk<<5)+krow0) ^ ((arow&7)<<3))];
                    acc[m] = mfma16(af, w, acc[m]);
                }
            }
            __builtin_amdgcn_s_setprio(0);
            #pragma unroll
            for (int m = 0; m < M; ++m)
                #pragma unroll
                for (int r = 0; r < 4; ++r) {
                    const int row = (m<<4) + rb + r;
                    sT[(row<<7) + (ncol ^ ((row&7)<<3))] =
                        ftof16(fmaxf(acc[m][r] + bg1c, 0.f));
                }
        }
        __syncthreads();                                        // S3

        // ======== phase 4: logits = u@Wg2 ; softmax ; y -> yB ========
        {
            f32x4 acc[M];
            #pragma unroll
            for (int m = 0; m < M; ++m) acc[m] = (f32x4){0.f,0.f,0.f,0.f};
            __builtin_amdgcn_s_setprio(1);
            #pragma unroll
            for (int kk = 0; kk < 4; ++kk) {
                const f16x8 w = *(const f16x8*)&WTg2[(size_t)ncol*C + (kk<<5) + krow0];
                #pragma unroll
                for (int m = 0; m < M; ++m) {
                    const f16x8 af = *(const f16x8*)&sT[(((m<<4)+arow)<<7) + (((kk<<5)+krow0) ^ ((arow&7)<<3))];
                    acc[m] = mfma16(af, w, acc[m]);
                }
            }
            __builtin_amdgcn_s_setprio(0);

            #pragma unroll
            for (int m = 0; m < M; ++m) {
                const f32x4 l = acc[m];
                float mx = fmaxf(fmaxf(l[0], l[1]), fmaxf(l[2], l[3]));
                mx = fmaxf(mx, __shfl_xor(mx, 16));
                mx = fmaxf(mx, __shfl_xor(mx, 32));
                const float e0 = __expf(l[0]-mx), e1 = __expf(l[1]-mx);
                const float e2 = __expf(l[2]-mx), e3 = __expf(l[3]-mx);
                float den = e0 + e1 + e2 + e3;
                den += __shfl_xor(den, 16);
                den += __shfl_xor(den, 32);
                const float inv = 1.0f / den;
                const int4 j4 = *(const int4*)&nidx[(size_t)(p0+m)*K + rb];
                float yp = 0.f;
                #pragma unroll
                for (int r = 0; r < 4; ++r) {
                    const int j = (r==0) ? j4.x : (r==1) ? j4.y : (r==2) ? j4.z : j4.w;
                    const float av = f16tof(alfB[(size_t)j*C + ncol]);
                    const int row = (m<<4) + rb + r;
                    const float pr = f16tof(sP[(row<<7) + (ncol ^ ((row&7)<<3))]);
                    const float ee = (r==0) ? e0 : (r==1) ? e1 : (r==2) ? e2 : e3;
                    yp = fmaf(ee, av + pr, yp);
                }
                yp *= inv;
                yp += __shfl_xor(yp, 16);
                yp += __shfl_xor(yp, 32);
                if (lane < 16)
                    yB[(size_t)(p0+m)*C + ncol] = ftof16(yp);
            }
        }
        __syncthreads();                                        // S4
    }
}

// ---------------------------------------------------------------------------
// Kernel 3: out = y @ W_down + b_down + x   (f16 MFMA GEMM, 64 rows/block)
// ---------------------------------------------------------------------------
__global__ __launch_bounds__(512) void k_down(
    const ushort_t* __restrict__ yB,
    const ushort_t* __restrict__ WTdn, const float* __restrict__ bdn,
    const float* __restrict__ x, float* __restrict__ out)
{
    __shared__ ushort_t sY[64*C];
    const int tid = threadIdx.x, lane = tid & 63, wv = tid >> 6;
    const int ncol = (wv<<4) + (lane&15), arow = lane&15;
    const int kgrp = lane>>4, krow0 = kgrp<<3;
    const int r0 = blockIdx.x * 64;

    {
        const int rY = tid>>3, cY = (tid&7)<<4;
        #pragma unroll
        for (int hf = 0; hf < 2; ++hf) {
            const uint4 v = *(const uint4*)&yB[(size_t)(r0+rY)*C + cY + hf*8];
            *(uint4*)&sY[(rY<<7) + ((cY + hf*8) ^ ((rY&7)<<3))] = v;
        }
    }
    __syncthreads();

    f16x8 wf[4]; f32x4 oacc[4];
    #pragma unroll
    for (int kk = 0; kk < 4; ++kk)
        wf[kk] = *(const f16x8*)&WTdn[(size_t)ncol*C + (kk<<5) + krow0];
    #pragma unroll
    for (int m = 0; m < 4; ++m) oacc[m] = (f32x4){0.f,0.f,0.f,0.f};
    __builtin_amdgcn_s_setprio(1);
    #pragma unroll
    for (int m = 0; m < 4; ++m)
        #pragma unroll
        for (int kk = 0; kk < 4; ++kk) {
            const int row = (m<<4) + arow;
            const f16x8 af = *(const f16x8*)&sY[(row<<7) + (((kk<<5)+krow0) ^ ((arow&7)<<3))];
            oacc[m] = mfma16(af, wf[kk], oacc[m]);
        }
    __builtin_amdgcn_s_setprio(0);
    const float bc = bdn[ncol];
    #pragma unroll
    for (int m = 0; m < 4; ++m)
        #pragma unroll
        for (int r = 0; r < 4; ++r) {
            const int row = (m<<4) + (kgrp<<2) + r;
            const size_t idx = (size_t)(r0+row)*C + ncol;
            out[idx] = oacc[m][r] + bc + x[idx];
        }
}

// ---------------------------------------------------------------------------
extern "C" void kernel_launch(void* const* d_in, const int* in_sizes, int n_in,
                              void* d_out, int out_size, void* d_ws, size_t ws_size,
                              hipStream_t stream)
{
    const float* x      = (const float*)d_in[0];
    const float* coords = (const float*)d_in[1];
    const int*   nidx   = (const int*)d_in[2];
    const float* W_top  = (const float*)d_in[3];
    const float* b_top  = (const float*)d_in[4];
    const float* W_down = (const float*)d_in[5];
    const float* b_down = (const float*)d_in[6];
    const float* W_phi  = (const float*)d_in[7];
    const float* b_phi  = (const float*)d_in[8];
    const float* W_psi  = (const float*)d_in[9];
    const float* b_psi  = (const float*)d_in[10];
    const float* W_alpha= (const float*)d_in[11];
    const float* b_alpha= (const float*)d_in[12];
    const float* W_d1   = (const float*)d_in[13];
    const float* b_d1   = (const float*)d_in[14];
    const float* W_d2   = (const float*)d_in[15];
    const float* b_d2   = (const float*)d_in[16];
    const float* W_g1   = (const float*)d_in[17];
    const float* b_g1   = (const float*)d_in[18];
    const float* W_g2   = (const float*)d_in[19];
    const float* b_g2   = (const float*)d_in[20];
    (void)b_g2; // softmax shift-invariant

    const int N = in_sizes[0] / C;

    ushort_t* WTt  = (ushort_t*)d_ws;
    ushort_t* WTp  = WTt  + C*C;
    ushort_t* WTs  = WTp  + C*C;
    ushort_t* WTa  = WTs  + C*C;
    ushort_t* WTd2 = WTa  + C*C;
    ushort_t* WTg1 = WTd2 + C*C;
    ushort_t* WTg2 = WTg1 + C*C;
    ushort_t* WTdn = WTg2 + C*C;
    ushort_t* phiB = WTdn + C*C;
    ushort_t* psiB = phiB + (size_t)N*C;
    ushort_t* alfB = psiB + (size_t)N*C;
    ushort_t* yB   = alfB + (size_t)N*C;
    float* out = (float*)d_out;

    hipLaunchKernelGGL(k_prep, dim3(4*C), dim3(C), 0, stream,
        W_top, W_phi, W_psi, W_alpha, WTt, WTp, WTs, WTa);
    hipLaunchKernelGGL(k_prep, dim3(4*C), dim3(C), 0, stream,
        W_d2, W_g1, W_g2, W_down, WTd2, WTg1, WTg2, WTdn);

    hipLaunchKernelGGL(k_qkv2, dim3(N / 64), dim3(512), 0, stream,
        x, WTt, b_top, WTp, b_phi, WTs, b_psi, WTa, b_alpha,
        phiB, psiB, alfB);

    const int ngroups = N / M;                 // 16384
    const int NBLK = 2048;
    const int gpb = (ngroups + NBLK - 1) / NBLK;
    hipLaunchKernelGGL(k_attn11, dim3(NBLK), dim3(512), 0, stream,
        phiB, psiB, alfB, coords, nidx,
        W_d1, b_d1, WTd2, b_d2, WTg1, b_g1, WTg2,
        yB, ngroups, gpb);

    hipLaunchKernelGGL(k_down, dim3(N / 64), dim3(512), 0, stream,
        yB, WTdn, b_down, x, out);
}